// Round 9
// baseline (778.131 us; speedup 1.0000x reference)
//
#include <hip/hip_runtime.h>
#include <hip/hip_bf16.h>

#define N_V 100000
#define N_E 20000
#define N_P 1600000
#define FDIM 128
#define HDIM 128
#define BN_EPS 1e-5f

#define EIDX_CAP 192   // per-wave LDS index buffer, edges (mean deg 80)
#define VIDX_CAP 64    // per-wave LDS index buffer, vertices (mean deg 16)

typedef __attribute__((ext_vector_type(8))) short short8;
typedef __attribute__((ext_vector_type(4))) float floatx4;

__device__ __forceinline__ float bf_lo(unsigned u) {
    return __uint_as_float(u << 16);
}
__device__ __forceinline__ float bf_hi(unsigned u) {
    return __uint_as_float(u & 0xffff0000u);
}
// fp32 -> bf16 bits, round-to-nearest-even
__device__ __forceinline__ unsigned short f2bf(float f) {
    unsigned u = __float_as_uint(f);
    return (unsigned short)((u + 0x7fffu + ((u >> 16) & 1u)) >> 16);
}

// accumulate 4 bf16 channels from one uint2 into s[0..3]
__device__ __forceinline__ void acc4(float* s, const uint2& u) {
    s[0] += bf_lo(u.x); s[1] += bf_hi(u.x);
    s[2] += bf_lo(u.y); s[3] += bf_hi(u.y);
}

// accumulate 8 bf16 channels from one uint4 into s[0..7]
__device__ __forceinline__ void acc8(float* s, const uint4& u) {
    s[0] += bf_lo(u.x); s[1] += bf_hi(u.x);
    s[2] += bf_lo(u.y); s[3] += bf_hi(u.y);
    s[4] += bf_lo(u.z); s[5] += bf_hi(u.z);
    s[6] += bf_lo(u.w); s[7] += bf_hi(u.w);
}

// ---------------------------------------------------------------------------
// Kernel A: h = X @ W + b via bf16 MFMA, computed as C^T = W^T · X^T.
// ---------------------------------------------------------------------------
#define GEMM_BLOCKS 625
#define WT_STRIDE 136   // 128 + 8 bf16 pad -> 2-way-only LDS conflicts
__global__ __launch_bounds__(256) void k_gemm_mfma(
    const float* __restrict__ X, const float* __restrict__ W,
    const float* __restrict__ bias, unsigned* __restrict__ h_u) {
    __shared__ unsigned short WTs[FDIM * WT_STRIDE];   // ~34 KB
    const int t = threadIdx.x;
    for (int idx = t; idx < FDIM * HDIM; idx += 256) {
        const int k = idx >> 7, m = idx & 127;
        WTs[m * WT_STRIDE + k] = f2bf(W[idx]);
    }
    __syncthreads();

    const int wave = t >> 6, lane = t & 63;
    const int quad = lane >> 4, sub = lane & 15;
    const int nstrips = N_V / 16;  // 6250, exact

    for (int s = blockIdx.x * 4 + wave; s < nstrips; s += GEMM_BLOCKS * 4) {
        const int row0 = s * 16;
        short8 xf[4];
        const float* xp = X + (size_t)(row0 + sub) * FDIM + quad * 8;
        #pragma unroll
        for (int kt = 0; kt < 4; ++kt) {
            const float4 a = *(const float4*)(xp + kt * 32);
            const float4 b2 = *(const float4*)(xp + kt * 32 + 4);
            short8 f;
            f[0] = (short)f2bf(a.x);  f[1] = (short)f2bf(a.y);
            f[2] = (short)f2bf(a.z);  f[3] = (short)f2bf(a.w);
            f[4] = (short)f2bf(b2.x); f[5] = (short)f2bf(b2.y);
            f[6] = (short)f2bf(b2.z); f[7] = (short)f2bf(b2.w);
            xf[kt] = f;
        }
        #pragma unroll
        for (int tile = 0; tile < 8; ++tile) {
            floatx4 acc = {0.f, 0.f, 0.f, 0.f};
            const unsigned short* wp =
                WTs + (tile * 16 + sub) * WT_STRIDE + quad * 8;
            #pragma unroll
            for (int kt = 0; kt < 4; ++kt) {
                const short8 af = *(const short8*)(wp + kt * 32);
                acc = __builtin_amdgcn_mfma_f32_16x16x32_bf16(af, xf[kt], acc,
                                                              0, 0, 0);
            }
            const int ch = tile * 16 + quad * 4;
            const float4 bb = *(const float4*)(bias + ch);
            const float c0 = acc[0] + bb.x, c1 = acc[1] + bb.y;
            const float c2 = acc[2] + bb.z, c3 = acc[3] + bb.w;
            const unsigned lo = (unsigned)f2bf(c0) | ((unsigned)f2bf(c1) << 16);
            const unsigned hi = (unsigned)f2bf(c2) | ((unsigned)f2bf(c3) << 16);
            uint2* dst = (uint2*)(h_u + (size_t)(row0 + sub) * 64 + (ch >> 1));
            *dst = make_uint2(lo, hi);
        }
    }
}

// ---------------------------------------------------------------------------
// Kernel B: per-channel sum & sumsq of bf16 h.  Vectorized uint4/lane.
// ---------------------------------------------------------------------------
#define BN_BLOCKS 400
#define BN_RPB 250
__global__ __launch_bounds__(256) void k_bn_stats(
    const unsigned* __restrict__ h_u, float* __restrict__ sums /* [256] */) {
    const int t = threadIdx.x;
    const int c8 = t & 15;            // channel octet: ch 8*c8 .. 8*c8+7
    const int rw = t >> 4;            // 16 row lanes
    const int r0 = blockIdx.x * BN_RPB;
    const int r1 = min(r0 + BN_RPB, N_V);
    float s[8] = {0.f,0.f,0.f,0.f,0.f,0.f,0.f,0.f};
    float ss[8] = {0.f,0.f,0.f,0.f,0.f,0.f,0.f,0.f};
    for (int r = r0 + rw; r < r1; r += 16) {
        const uint4 u = *(const uint4*)(h_u + (size_t)r * 64 + c8 * 4);
        const float x0 = bf_lo(u.x), x1 = bf_hi(u.x);
        const float x2 = bf_lo(u.y), x3 = bf_hi(u.y);
        const float x4 = bf_lo(u.z), x5 = bf_hi(u.z);
        const float x6 = bf_lo(u.w), x7 = bf_hi(u.w);
        s[0]+=x0; ss[0]+=x0*x0;  s[1]+=x1; ss[1]+=x1*x1;
        s[2]+=x2; ss[2]+=x2*x2;  s[3]+=x3; ss[3]+=x3*x3;
        s[4]+=x4; ss[4]+=x4*x4;  s[5]+=x5; ss[5]+=x5*x5;
        s[6]+=x6; ss[6]+=x6*x6;  s[7]+=x7; ss[7]+=x7*x7;
    }
    #pragma unroll
    for (int k = 0; k < 8; ++k) {
        s[k]  += __shfl_xor(s[k], 16);  s[k]  += __shfl_xor(s[k], 32);
        ss[k] += __shfl_xor(ss[k], 16); ss[k] += __shfl_xor(ss[k], 32);
    }
    __shared__ float ls[128], lss[128];
    for (int k = t; k < 128; k += 256) { ls[k] = 0.f; lss[k] = 0.f; }
    __syncthreads();
    if ((t & 63) < 16) {
        #pragma unroll
        for (int k = 0; k < 8; ++k) {
            atomicAdd(&ls[c8 * 8 + k], s[k]);
            atomicAdd(&lss[c8 * 8 + k], ss[k]);
        }
    }
    __syncthreads();
    if (t < 128) {
        atomicAdd(&sums[t],       ls[t]);
        atomicAdd(&sums[128 + t], lss[t]);
    }
}

// ---------------------------------------------------------------------------
// Kernel C: finalize BN -> scale/shift
// ---------------------------------------------------------------------------
__global__ void k_bn_final(const float* __restrict__ sums,
                           const float* __restrict__ gamma,
                           const float* __restrict__ beta,
                           float* __restrict__ scale, float* __restrict__ shift) {
    const int c = threadIdx.x;
    const float inv_n = 1.0f / (float)N_V;
    const float mu  = sums[c] * inv_n;
    const float var = sums[128 + c] * inv_n - mu * mu;
    const float inv = rsqrtf(var + BN_EPS);
    const float sc  = gamma[c] * inv;
    scale[c] = sc;
    shift[c] = beta[c] - mu * sc;
}

// ---------------------------------------------------------------------------
// Kernel D1: global histograms of edge and vertex ids (int4 loads).
// [R8 rewrite: replaces the two-phase bucket sort.  R3/R4 proved adjacency
// ORDER doesn't affect gather FETCH (compulsory-miss-dominated), so all
// ordering machinery was wasted work — direct counting sort suffices.]
// ---------------------------------------------------------------------------
#define HIST_BLOCKS 1024
__global__ __launch_bounds__(256) void k_hist(
    const int* __restrict__ vid, const int* __restrict__ eid,
    int* __restrict__ histE, int* __restrict__ histV) {
    const int tid = blockIdx.x * 256 + threadIdx.x;
    for (int i = tid; i < N_P / 4; i += HIST_BLOCKS * 256) {
        const int4 e4 = ((const int4*)eid)[i];
        const int4 v4 = ((const int4*)vid)[i];
        atomicAdd(&histE[e4.x], 1); atomicAdd(&histE[e4.y], 1);
        atomicAdd(&histE[e4.z], 1); atomicAdd(&histE[e4.w], 1);
        atomicAdd(&histV[v4.x], 1); atomicAdd(&histV[v4.y], 1);
        atomicAdd(&histV[v4.z], 1); atomicAdd(&histV[v4.w], 1);
    }
}

// ---------------------------------------------------------------------------
// Kernel D2: exclusive scan of both histograms.  Block 0 scans E (20000),
// block 1 scans V (100000).  Chunk-per-thread serial sum + Hillis-Steele
// block scan + serial write-back.
// ---------------------------------------------------------------------------
__global__ __launch_bounds__(1024) void k_scan(
    const int* __restrict__ histE, int* __restrict__ eoff, int* __restrict__ ecnt,
    const int* __restrict__ histV, int* __restrict__ voff, int* __restrict__ vcnt) {
    __shared__ int partial[1024];
    const int t = threadIdx.x;
    const int* hist; int* off; int* cnt; int n;
    if (blockIdx.x == 0) { hist = histE; off = eoff; cnt = ecnt; n = N_E; }
    else                 { hist = histV; off = voff; cnt = vcnt; n = N_V; }
    const int chunk = (n + 1023) / 1024;
    const int lo = t * chunk, hi = min(lo + chunk, n);
    int s = 0;
    for (int i = lo; i < hi; ++i) s += hist[i];
    partial[t] = s;
    __syncthreads();
    for (int d = 1; d < 1024; d <<= 1) {
        int x = (t >= d) ? partial[t - d] : 0;
        __syncthreads(); partial[t] += x; __syncthreads();
    }
    int base = t ? partial[t - 1] : 0;
    for (int i = lo; i < hi; ++i) {
        const int h = hist[i];
        off[i] = base; cnt[i] = h; base += h;
    }
}

// ---------------------------------------------------------------------------
// Kernel D3: scatter pairs into flat CSR via atomic position counters.
// 3.2M global atomics over 120K counters spread across ~128 L2 channels —
// unlike R7's block-local LDS atomics, this parallelizes.
// ---------------------------------------------------------------------------
#define SCAT_BLOCKS 1024
__global__ __launch_bounds__(256) void k_scatter(
    const int* __restrict__ vid, const int* __restrict__ eid,
    const int* __restrict__ eoff, const int* __restrict__ voff,
    int* __restrict__ curE, int* __restrict__ curV,
    int* __restrict__ csrE, int* __restrict__ csrV) {
    const int tid = blockIdx.x * 256 + threadIdx.x;
    for (int i = tid; i < N_P / 4; i += SCAT_BLOCKS * 256) {
        const int4 e4 = ((const int4*)eid)[i];
        const int4 v4 = ((const int4*)vid)[i];
        int p;
        p = atomicAdd(&curE[e4.x], 1); csrE[eoff[e4.x] + p] = v4.x;
        p = atomicAdd(&curE[e4.y], 1); csrE[eoff[e4.y] + p] = v4.y;
        p = atomicAdd(&curE[e4.z], 1); csrE[eoff[e4.z] + p] = v4.z;
        p = atomicAdd(&curE[e4.w], 1); csrE[eoff[e4.w] + p] = v4.w;
        p = atomicAdd(&curV[v4.x], 1); csrV[voff[v4.x] + p] = e4.x;
        p = atomicAdd(&curV[v4.y], 1); csrV[voff[v4.y] + p] = e4.y;
        p = atomicAdd(&curV[v4.z], 1); csrV[voff[v4.z] + p] = e4.z;
        p = atomicAdd(&curV[v4.w], 1); csrV[voff[v4.w] + p] = e4.w;
    }
}

// ---------------------------------------------------------------------------
// Kernel F: per-edge gather-reduce, CHANNEL-HALF split across XCD groups.
// blockIdx%8 selects the XCD; XCDs 0-3 process channels 0..63, XCDs 4-7
// channels 64..127 -> per-XCD L2 holds 128 B/row, cutting compulsory fetch.
// [measured R5/R6]
// ---------------------------------------------------------------------------
__global__ __launch_bounds__(256) void k_edge_gather(
    const unsigned* __restrict__ h_u, const int* __restrict__ csrE,
    const int* __restrict__ eoff, const int* __restrict__ ecnt,
    const float* __restrict__ scale, const float* __restrict__ shift,
    unsigned* __restrict__ xe_u) {
    __shared__ int ib[4][EIDX_CAP];
    const int b = blockIdx.x;                   // 0 .. 2*(N_E/4)-1
    const int xcd = b & 7;
    const int half = xcd >> 2;                  // channel half 0/1
    const int grp = (b >> 3) * 4 + (xcd & 3);   // edge group 0..N_E/4-1
    const int wave = threadIdx.x >> 6;
    const int e = grp * 4 + wave;
    const int l = threadIdx.x & 63;
    const int rg = l >> 4, c = l & 15;          // row-in-group, channel-pair
    const int wbase = half * 32 + 2 * c;        // word offset within row
    int o = 0, n = 0;
    if (e < N_E) { o = eoff[e]; n = ecnt[e]; }
    const int nc = min(n, EIDX_CAP);
    int* mi = ib[wave];
    for (int i = l; i < nc; i += 64) mi[i] = csrE[o + i];
    __syncthreads();

    float s[4] = {0.f, 0.f, 0.f, 0.f};
    int j = 0;
    for (; j + 31 < nc; j += 32) {
        const int r0 = mi[j + rg],      r1 = mi[j + 4 + rg];
        const int r2 = mi[j + 8 + rg],  r3 = mi[j + 12 + rg];
        const int r4 = mi[j + 16 + rg], r5 = mi[j + 20 + rg];
        const int r6 = mi[j + 24 + rg], r7 = mi[j + 28 + rg];
        const uint2 u0 = *(const uint2*)(h_u + (size_t)r0 * 64 + wbase);
        const uint2 u1 = *(const uint2*)(h_u + (size_t)r1 * 64 + wbase);
        const uint2 u2 = *(const uint2*)(h_u + (size_t)r2 * 64 + wbase);
        const uint2 u3 = *(const uint2*)(h_u + (size_t)r3 * 64 + wbase);
        const uint2 u4 = *(const uint2*)(h_u + (size_t)r4 * 64 + wbase);
        const uint2 u5 = *(const uint2*)(h_u + (size_t)r5 * 64 + wbase);
        const uint2 u6 = *(const uint2*)(h_u + (size_t)r6 * 64 + wbase);
        const uint2 u7 = *(const uint2*)(h_u + (size_t)r7 * 64 + wbase);
        acc4(s, u0); acc4(s, u1); acc4(s, u2); acc4(s, u3);
        acc4(s, u4); acc4(s, u5); acc4(s, u6); acc4(s, u7);
    }
    for (; j + 15 < nc; j += 16) {
        const int r0 = mi[j + rg],     r1 = mi[j + 4 + rg];
        const int r2 = mi[j + 8 + rg], r3 = mi[j + 12 + rg];
        const uint2 u0 = *(const uint2*)(h_u + (size_t)r0 * 64 + wbase);
        const uint2 u1 = *(const uint2*)(h_u + (size_t)r1 * 64 + wbase);
        const uint2 u2 = *(const uint2*)(h_u + (size_t)r2 * 64 + wbase);
        const uint2 u3 = *(const uint2*)(h_u + (size_t)r3 * 64 + wbase);
        acc4(s, u0); acc4(s, u1); acc4(s, u2); acc4(s, u3);
    }
    for (; j < nc; j += 4) {
        if (j + rg < nc) {
            const int r = mi[j + rg];
            const uint2 u = *(const uint2*)(h_u + (size_t)r * 64 + wbase);
            acc4(s, u);
        }
    }
    // overflow path (n > EIDX_CAP), statistically negligible but correct
    for (int jj = nc; jj < n; jj += 4) {
        if (jj + rg < n) {
            const int r = csrE[o + jj + rg];
            const uint2 u = *(const uint2*)(h_u + (size_t)r * 64 + wbase);
            acc4(s, u);
        }
    }
    #pragma unroll
    for (int k = 0; k < 4; ++k) {
        s[k] += __shfl_xor(s[k], 16);
        s[k] += __shfl_xor(s[k], 32);
    }
    if (e < N_E && rg == 0) {
        float m[4] = {0.f, 0.f, 0.f, 0.f};
        if (n > 0) {
            const float rc = 1.0f / (float)n;
            const float4 sc4 = ((const float4*)scale)[half * 16 + c];
            const float4 sh4 = ((const float4*)shift)[half * 16 + c];
            m[0] = sc4.x * s[0] * rc + sh4.x;
            m[1] = sc4.y * s[1] * rc + sh4.y;
            m[2] = sc4.z * s[2] * rc + sh4.z;
            m[3] = sc4.w * s[3] * rc + sh4.w;
        }
        uint2 pk;
        pk.x = (unsigned)f2bf(m[0]) | ((unsigned)f2bf(m[1]) << 16);
        pk.y = (unsigned)f2bf(m[2]) | ((unsigned)f2bf(m[3]) << 16);
        *(uint2*)(xe_u + (size_t)e * 64 + wbase) = pk;
    }
}

// ---------------------------------------------------------------------------
// Kernel G: per-vertex gather-reduce + ReLU.  Full-row uint4, one wave per
// vertex, LDS index prefetch, 16-row main loop.  [measured R6/R8: ~48 us]
// ---------------------------------------------------------------------------
__global__ __launch_bounds__(256) void k_vert_gather(
    const unsigned* __restrict__ xe_u, const int* __restrict__ csrV,
    const int* __restrict__ voff, const int* __restrict__ vcnt,
    float* __restrict__ out) {
    __shared__ int ib[4][VIDX_CAP];
    const int wave = threadIdx.x >> 6;
    const int v = blockIdx.x * 4 + wave;
    const int l = threadIdx.x & 63;
    const int g = l >> 4, c = l & 15;
    int o = 0, n = 0;
    if (v < N_V) { o = voff[v]; n = vcnt[v]; }
    const int nc = min(n, VIDX_CAP);
    int* mi = ib[wave];
    for (int i = l; i < nc; i += 64) mi[i] = csrV[o + i];
    __syncthreads();

    float s[8] = {0.f, 0.f, 0.f, 0.f, 0.f, 0.f, 0.f, 0.f};
    int j = 0;
    for (; j + 15 < nc; j += 16) {
        const int r0 = mi[j + g],     r1 = mi[j + 4 + g];
        const int r2 = mi[j + 8 + g], r3 = mi[j + 12 + g];
        const uint4 u0 = *(const uint4*)(xe_u + (size_t)r0 * 64 + 4 * c);
        const uint4 u1 = *(const uint4*)(xe_u + (size_t)r1 * 64 + 4 * c);
        const uint4 u2 = *(const uint4*)(xe_u + (size_t)r2 * 64 + 4 * c);
        const uint4 u3 = *(const uint4*)(xe_u + (size_t)r3 * 64 + 4 * c);
        acc8(s, u0); acc8(s, u1); acc8(s, u2); acc8(s, u3);
    }
    for (; j < nc; j += 4) {
        if (j + g < nc) {
            const int r = mi[j + g];
            const uint4 u = *(const uint4*)(xe_u + (size_t)r * 64 + 4 * c);
            acc8(s, u);
        }
    }
    // overflow path (n > VIDX_CAP), statistically negligible but correct
    for (int jj = nc; jj < n; jj += 4) {
        if (jj + g < n) {
            const int r = csrV[o + jj + g];
            const uint4 u = *(const uint4*)(xe_u + (size_t)r * 64 + 4 * c);
            acc8(s, u);
        }
    }
    #pragma unroll
    for (int k = 0; k < 8; ++k) {
        s[k] += __shfl_xor(s[k], 16);
        s[k] += __shfl_xor(s[k], 32);
    }
    if (v < N_V && g == 0) {
        const float rc = 1.0f / (float)max(n, 1);
        float4 r0, r1;
        r0.x = fmaxf(s[0] * rc, 0.f);
        r0.y = fmaxf(s[1] * rc, 0.f);
        r0.z = fmaxf(s[2] * rc, 0.f);
        r0.w = fmaxf(s[3] * rc, 0.f);
        r1.x = fmaxf(s[4] * rc, 0.f);
        r1.y = fmaxf(s[5] * rc, 0.f);
        r1.z = fmaxf(s[6] * rc, 0.f);
        r1.w = fmaxf(s[7] * rc, 0.f);
        ((float4*)out)[(size_t)v * 32 + 2 * c]     = r0;
        ((float4*)out)[(size_t)v * 32 + 2 * c + 1] = r1;
    }
}

// ---------------------------------------------------------------------------
extern "C" void kernel_launch(void* const* d_in, const int* in_sizes, int n_in,
                              void* d_out, int out_size, void* d_ws, size_t ws_size,
                              hipStream_t stream) {
    const float* X     = (const float*)d_in[0];
    const int*   vid   = (const int*)d_in[1];
    const int*   eid   = (const int*)d_in[2];
    const float* W     = (const float*)d_in[3];
    const float* b     = (const float*)d_in[4];
    const float* gamma = (const float*)d_in[5];
    const float* beta  = (const float*)d_in[6];
    float* out = (float*)d_out;

    // workspace layout
    char* ws = (char*)d_ws;
    unsigned* h_u   = (unsigned*)ws;  ws += (size_t)N_V * 64 * 4;   // 25.6 MB
    unsigned* xe_u  = (unsigned*)ws;  ws += (size_t)N_E * 64 * 4;   //  5.1 MB
    int* csrE = (int*)ws;             ws += (size_t)N_P * 4;        //  6.4 MB
    int* csrV = (int*)ws;             ws += (size_t)N_P * 4;        //  6.4 MB
    int* eoff = (int*)ws;             ws += (size_t)N_E * 4;
    int* ecnt = (int*)ws;             ws += (size_t)N_E * 4;
    int* voff = (int*)ws;             ws += (size_t)N_V * 4;
    int* vcnt = (int*)ws;             ws += (size_t)N_V * 4;
    // --- zeroed region ---
    char* zbase = ws;
    int*   histE = (int*)ws;          ws += (size_t)N_E * 4;        // 80 KB
    int*   histV = (int*)ws;          ws += (size_t)N_V * 4;        // 400 KB
    int*   curE  = (int*)ws;          ws += (size_t)N_E * 4;        // 80 KB
    int*   curV  = (int*)ws;          ws += (size_t)N_V * 4;        // 400 KB
    float* sums  = (float*)ws;        ws += 256 * 4;
    // --- end zeroed region ---
    float* scale = (float*)ws;        ws += 128 * 4;
    float* shift = (float*)ws;        ws += 128 * 4;

    hipMemsetAsync(zbase, 0, (size_t)((char*)scale - zbase), stream);

    k_gemm_mfma<<<GEMM_BLOCKS, 256, 0, stream>>>(X, W, b, h_u);
    k_bn_stats<<<BN_BLOCKS, 256, 0, stream>>>(h_u, sums);
    k_bn_final<<<1, 128, 0, stream>>>(sums, gamma, beta, scale, shift);

    // single-pass counting-sort CSR build (replaces bucket sort + 2x k_csr)
    k_hist<<<HIST_BLOCKS, 256, 0, stream>>>(vid, eid, histE, histV);
    k_scan<<<2, 1024, 0, stream>>>(histE, eoff, ecnt, histV, voff, vcnt);
    k_scatter<<<SCAT_BLOCKS, 256, 0, stream>>>(vid, eid, eoff, voff,
                                               curE, curV, csrE, csrV);

    // edge: 2 channel-halves x (N_E/4) groups; blockIdx%8 pins XCD,
    // XCDs 0-3 -> half 0, XCDs 4-7 -> half 1.
    k_edge_gather<<<(N_E / 4) * 2, 256, 0, stream>>>(h_u, csrE, eoff, ecnt,
                                                     scale, shift, xe_u);
    // vertex: full-row, one wave per vertex
    k_vert_gather<<<(N_V + 3) / 4, 256, 0, stream>>>(xe_u, csrV, voff, vcnt,
                                                     out);
}

// Round 10
// 285.344 us; speedup vs baseline: 2.7270x; 2.7270x over previous
//
#include <hip/hip_runtime.h>
#include <hip/hip_bf16.h>

#define N_V 100000
#define N_E 20000
#define N_P 1600000
#define FDIM 128
#define HDIM 128
#define BN_EPS 1e-5f

// ---- bucket/sort geometry ----
#define SORT_C 4096
#define SORT_BLOCKS ((N_P + SORT_C - 1) / SORT_C)   // 391
#define NB_E 313                   // edge buckets (64 edges each)
#define EB_SHIFT 6
#define EB_REGION 9216             // slots per edge bucket region
#define EB_SORT 5888               // max valid entries per bucket (mean 5112)
#define NB_V 391                   // vertex buckets (256 vertices each)
#define VB_SHIFT 8
#define VB_REGION 8192
#define VB_SORT 4608               // max valid entries per bucket (mean 4096)
#define SENTINEL 0xFFFFFFFFu

#define EIDX_CAP 192   // per-wave LDS index buffer, edges (mean deg 80)
#define VIDX_CAP 64    // per-wave LDS index buffer, vertices (mean deg 16)

typedef __attribute__((ext_vector_type(8))) short short8;
typedef __attribute__((ext_vector_type(4))) float floatx4;

__device__ __forceinline__ float bf_lo(unsigned u) {
    return __uint_as_float(u << 16);
}
__device__ __forceinline__ float bf_hi(unsigned u) {
    return __uint_as_float(u & 0xffff0000u);
}
// fp32 -> bf16 bits, round-to-nearest-even
__device__ __forceinline__ unsigned short f2bf(float f) {
    unsigned u = __float_as_uint(f);
    return (unsigned short)((u + 0x7fffu + ((u >> 16) & 1u)) >> 16);
}

// accumulate 4 bf16 channels from one uint2 into s[0..3]
__device__ __forceinline__ void acc4(float* s, const uint2& u) {
    s[0] += bf_lo(u.x); s[1] += bf_hi(u.x);
    s[2] += bf_lo(u.y); s[3] += bf_hi(u.y);
}

// accumulate 8 bf16 channels from one uint4 into s[0..7]
__device__ __forceinline__ void acc8(float* s, const uint4& u) {
    s[0] += bf_lo(u.x); s[1] += bf_hi(u.x);
    s[2] += bf_lo(u.y); s[3] += bf_hi(u.y);
    s[4] += bf_lo(u.z); s[5] += bf_hi(u.z);
    s[6] += bf_lo(u.w); s[7] += bf_hi(u.w);
}

// ---------------------------------------------------------------------------
// Kernel A: h = X @ W + b via bf16 MFMA, computed as C^T = W^T · X^T.
// ---------------------------------------------------------------------------
#define GEMM_BLOCKS 625
#define WT_STRIDE 136   // 128 + 8 bf16 pad -> 2-way-only LDS conflicts
__global__ __launch_bounds__(256) void k_gemm_mfma(
    const float* __restrict__ X, const float* __restrict__ W,
    const float* __restrict__ bias, unsigned* __restrict__ h_u) {
    __shared__ unsigned short WTs[FDIM * WT_STRIDE];   // ~34 KB
    const int t = threadIdx.x;
    for (int idx = t; idx < FDIM * HDIM; idx += 256) {
        const int k = idx >> 7, m = idx & 127;
        WTs[m * WT_STRIDE + k] = f2bf(W[idx]);
    }
    __syncthreads();

    const int wave = t >> 6, lane = t & 63;
    const int quad = lane >> 4, sub = lane & 15;
    const int nstrips = N_V / 16;  // 6250, exact

    for (int s = blockIdx.x * 4 + wave; s < nstrips; s += GEMM_BLOCKS * 4) {
        const int row0 = s * 16;
        short8 xf[4];
        const float* xp = X + (size_t)(row0 + sub) * FDIM + quad * 8;
        #pragma unroll
        for (int kt = 0; kt < 4; ++kt) {
            const float4 a = *(const float4*)(xp + kt * 32);
            const float4 b2 = *(const float4*)(xp + kt * 32 + 4);
            short8 f;
            f[0] = (short)f2bf(a.x);  f[1] = (short)f2bf(a.y);
            f[2] = (short)f2bf(a.z);  f[3] = (short)f2bf(a.w);
            f[4] = (short)f2bf(b2.x); f[5] = (short)f2bf(b2.y);
            f[6] = (short)f2bf(b2.z); f[7] = (short)f2bf(b2.w);
            xf[kt] = f;
        }
        #pragma unroll
        for (int tile = 0; tile < 8; ++tile) {
            floatx4 acc = {0.f, 0.f, 0.f, 0.f};
            const unsigned short* wp =
                WTs + (tile * 16 + sub) * WT_STRIDE + quad * 8;
            #pragma unroll
            for (int kt = 0; kt < 4; ++kt) {
                const short8 af = *(const short8*)(wp + kt * 32);
                acc = __builtin_amdgcn_mfma_f32_16x16x32_bf16(af, xf[kt], acc,
                                                              0, 0, 0);
            }
            const int ch = tile * 16 + quad * 4;
            const float4 bb = *(const float4*)(bias + ch);
            const float c0 = acc[0] + bb.x, c1 = acc[1] + bb.y;
            const float c2 = acc[2] + bb.z, c3 = acc[3] + bb.w;
            const unsigned lo = (unsigned)f2bf(c0) | ((unsigned)f2bf(c1) << 16);
            const unsigned hi = (unsigned)f2bf(c2) | ((unsigned)f2bf(c3) << 16);
            uint2* dst = (uint2*)(h_u + (size_t)(row0 + sub) * 64 + (ch >> 1));
            *dst = make_uint2(lo, hi);
        }
    }
}

// ---------------------------------------------------------------------------
// Kernel B: per-channel sum & sumsq of bf16 h.  Vectorized uint4/lane.
// ---------------------------------------------------------------------------
#define BN_BLOCKS 400
#define BN_RPB 250
__global__ __launch_bounds__(256) void k_bn_stats(
    const unsigned* __restrict__ h_u, float* __restrict__ sums /* [256] */) {
    const int t = threadIdx.x;
    const int c8 = t & 15;            // channel octet: ch 8*c8 .. 8*c8+7
    const int rw = t >> 4;            // 16 row lanes
    const int r0 = blockIdx.x * BN_RPB;
    const int r1 = min(r0 + BN_RPB, N_V);
    float s[8] = {0.f,0.f,0.f,0.f,0.f,0.f,0.f,0.f};
    float ss[8] = {0.f,0.f,0.f,0.f,0.f,0.f,0.f,0.f};
    for (int r = r0 + rw; r < r1; r += 16) {
        const uint4 u = *(const uint4*)(h_u + (size_t)r * 64 + c8 * 4);
        const float x0 = bf_lo(u.x), x1 = bf_hi(u.x);
        const float x2 = bf_lo(u.y), x3 = bf_hi(u.y);
        const float x4 = bf_lo(u.z), x5 = bf_hi(u.z);
        const float x6 = bf_lo(u.w), x7 = bf_hi(u.w);
        s[0]+=x0; ss[0]+=x0*x0;  s[1]+=x1; ss[1]+=x1*x1;
        s[2]+=x2; ss[2]+=x2*x2;  s[3]+=x3; ss[3]+=x3*x3;
        s[4]+=x4; ss[4]+=x4*x4;  s[5]+=x5; ss[5]+=x5*x5;
        s[6]+=x6; ss[6]+=x6*x6;  s[7]+=x7; ss[7]+=x7*x7;
    }
    #pragma unroll
    for (int k = 0; k < 8; ++k) {
        s[k]  += __shfl_xor(s[k], 16);  s[k]  += __shfl_xor(s[k], 32);
        ss[k] += __shfl_xor(ss[k], 16); ss[k] += __shfl_xor(ss[k], 32);
    }
    __shared__ float ls[128], lss[128];
    for (int k = t; k < 128; k += 256) { ls[k] = 0.f; lss[k] = 0.f; }
    __syncthreads();
    if ((t & 63) < 16) {
        #pragma unroll
        for (int k = 0; k < 8; ++k) {
            atomicAdd(&ls[c8 * 8 + k], s[k]);
            atomicAdd(&lss[c8 * 8 + k], ss[k]);
        }
    }
    __syncthreads();
    if (t < 128) {
        atomicAdd(&sums[t],       ls[t]);
        atomicAdd(&sums[128 + t], lss[t]);
    }
}

// ---------------------------------------------------------------------------
// Kernel C: finalize BN -> scale/shift
// ---------------------------------------------------------------------------
__global__ void k_bn_final(const float* __restrict__ sums,
                           const float* __restrict__ gamma,
                           const float* __restrict__ beta,
                           float* __restrict__ scale, float* __restrict__ shift) {
    const int c = threadIdx.x;
    const float inv_n = 1.0f / (float)N_V;
    const float mu  = sums[c] * inv_n;
    const float var = sums[128 + c] * inv_n - mu * mu;
    const float inv = rsqrtf(var + BN_EPS);
    const float sc  = gamma[c] * inv;
    scale[c] = sc;
    shift[c] = beta[c] - mu * sc;
}

// ---------------------------------------------------------------------------
// Kernel D: dual-direction LDS-staged chunk sort, line-aligned full-line
// flush.  [R9 lesson: direct global scatter = 16x write amplification
// (204 MB for 12.8 MB payload); this bucket+full-line-flush design is the
// right structure.  R9 change: int4 input loads, uint4 flush writes.]
// ---------------------------------------------------------------------------
__global__ __launch_bounds__(256) void k_sort_dual(
    const int* __restrict__ vid, const int* __restrict__ eid,
    int* __restrict__ gcntE, int* __restrict__ gcntV,
    unsigned* __restrict__ partE, unsigned* __restrict__ partV) {
    __shared__ unsigned stageE[SORT_C];          // 16 KB
    __shared__ unsigned stageV[SORT_C];          // 16 KB
    __shared__ int histE[NB_E], curE[NB_E], offsE[NB_E], gbaseE[NB_E];
    __shared__ int histV[NB_V], curV[NB_V], offsV[NB_V], gbaseV[NB_V];
    __shared__ int partial[256];
    const int t = threadIdx.x;
    const int p0 = blockIdx.x * SORT_C;
    const int n = min(SORT_C, N_P - p0);         // always divisible by 4
    const int n4 = n >> 2;
    const int4* e4p = (const int4*)(eid + p0);
    const int4* v4p = (const int4*)(vid + p0);

    for (int k = t; k < NB_E; k += 256) histE[k] = 0;
    for (int k = t; k < NB_V; k += 256) histV[k] = 0;
    __syncthreads();
    for (int i = t; i < n4; i += 256) {
        const int4 e4 = e4p[i];
        const int4 v4 = v4p[i];
        atomicAdd(&histE[((unsigned)e4.x) >> EB_SHIFT], 1);
        atomicAdd(&histE[((unsigned)e4.y) >> EB_SHIFT], 1);
        atomicAdd(&histE[((unsigned)e4.z) >> EB_SHIFT], 1);
        atomicAdd(&histE[((unsigned)e4.w) >> EB_SHIFT], 1);
        atomicAdd(&histV[((unsigned)v4.x) >> VB_SHIFT], 1);
        atomicAdd(&histV[((unsigned)v4.y) >> VB_SHIFT], 1);
        atomicAdd(&histV[((unsigned)v4.z) >> VB_SHIFT], 1);
        atomicAdd(&histV[((unsigned)v4.w) >> VB_SHIFT], 1);
    }
    __syncthreads();
    // scan E
    {
        constexpr int G = (NB_E + 255) / 256;
        int loc[G]; int s = 0;
        #pragma unroll
        for (int g = 0; g < G; ++g) {
            int idx = t * G + g; loc[g] = s;
            if (idx < NB_E) s += histE[idx];
        }
        partial[t] = s;
        __syncthreads();
        for (int d = 1; d < 256; d <<= 1) {
            int x = (t >= d) ? partial[t - d] : 0;
            __syncthreads(); partial[t] += x; __syncthreads();
        }
        const int base = t ? partial[t - 1] : 0;
        #pragma unroll
        for (int g = 0; g < G; ++g) {
            int idx = t * G + g;
            if (idx < NB_E) { offsE[idx] = base + loc[g]; curE[idx] = base + loc[g]; }
        }
        __syncthreads();
    }
    // scan V
    {
        constexpr int G = (NB_V + 255) / 256;
        int loc[G]; int s = 0;
        #pragma unroll
        for (int g = 0; g < G; ++g) {
            int idx = t * G + g; loc[g] = s;
            if (idx < NB_V) s += histV[idx];
        }
        partial[t] = s;
        __syncthreads();
        for (int d = 1; d < 256; d <<= 1) {
            int x = (t >= d) ? partial[t - d] : 0;
            __syncthreads(); partial[t] += x; __syncthreads();
        }
        const int base = t ? partial[t - 1] : 0;
        #pragma unroll
        for (int g = 0; g < G; ++g) {
            int idx = t * G + g;
            if (idx < NB_V) { offsV[idx] = base + loc[g]; curV[idx] = base + loc[g]; }
        }
        __syncthreads();
    }
    // place both directions (4 entries per thread, int4 loads)
    for (int i = t; i < n4; i += 256) {
        const int4 e4 = e4p[i];
        const int4 v4 = v4p[i];
        #pragma unroll
        for (int q = 0; q < 4; ++q) {
            const int ev = (q == 0) ? e4.x : (q == 1) ? e4.y : (q == 2) ? e4.z : e4.w;
            const int vv = (q == 0) ? v4.x : (q == 1) ? v4.y : (q == 2) ? v4.z : v4.w;
            const unsigned pkE = ((unsigned)(ev & 63) << 17) | (unsigned)vv;
            stageE[atomicAdd(&curE[(unsigned)ev >> EB_SHIFT], 1)] = pkE;
            const unsigned pkV = ((unsigned)(vv & 255) << 15) | (unsigned)ev;
            stageV[atomicAdd(&curV[(unsigned)vv >> VB_SHIFT], 1)] = pkV;
        }
    }
    __syncthreads();
    // allocate line-aligned global space
    for (int k = t; k < NB_E; k += 256) {
        const int c = histE[k];
        gbaseE[k] = c ? atomicAdd(&gcntE[k], (c + 15) & ~15) : 0;
    }
    for (int k = t; k < NB_V; k += 256) {
        const int c = histV[k];
        gbaseV[k] = c ? atomicAdd(&gcntV[k], (c + 15) & ~15) : 0;
    }
    __syncthreads();
    // flush E (uint4 writes; cpad multiple of 16, dst 64B aligned)
    for (int k = t >> 3; k < NB_E; k += 32) {
        const int c = histE[k];
        if (c == 0) continue;
        int cpad = (c + 15) & ~15;
        const int gb = gbaseE[k];
        if (gb >= EB_REGION) continue;
        cpad = min(cpad, EB_REGION - gb);
        unsigned* dst = partE + (size_t)k * EB_REGION + gb;
        const int lo = offsE[k];
        for (int j = (t & 7) * 4; j + 3 < cpad; j += 32) {
            uint4 w;
            w.x = (j + 0 < c) ? stageE[lo + j + 0] : SENTINEL;
            w.y = (j + 1 < c) ? stageE[lo + j + 1] : SENTINEL;
            w.z = (j + 2 < c) ? stageE[lo + j + 2] : SENTINEL;
            w.w = (j + 3 < c) ? stageE[lo + j + 3] : SENTINEL;
            *(uint4*)(dst + j) = w;
        }
    }
    // flush V
    for (int k = t >> 3; k < NB_V; k += 32) {
        const int c = histV[k];
        if (c == 0) continue;
        int cpad = (c + 15) & ~15;
        const int gb = gbaseV[k];
        if (gb >= VB_REGION) continue;
        cpad = min(cpad, VB_REGION - gb);
        unsigned* dst = partV + (size_t)k * VB_REGION + gb;
        const int lo = offsV[k];
        for (int j = (t & 7) * 4; j + 3 < cpad; j += 32) {
            uint4 w;
            w.x = (j + 0 < c) ? stageV[lo + j + 0] : SENTINEL;
            w.y = (j + 1 < c) ? stageV[lo + j + 1] : SENTINEL;
            w.z = (j + 2 < c) ? stageV[lo + j + 2] : SENTINEL;
            w.w = (j + 3 < c) ? stageV[lo + j + 3] : SENTINEL;
            *(uint4*)(dst + j) = w;
        }
    }
}

// ---------------------------------------------------------------------------
// Kernel E: bucket region -> compact sorted CSR.  [R9 rewrite: ballot-
// compact phase removed — sentinels skipped inline, src re-read from L2
// (37 KB/block).  uint4 src reads + uint4 B write-out.  LDS -24 KB/block.]
// ---------------------------------------------------------------------------
template <int NKEY, int PACK_SHIFT, int CAP, int REGION, int STRIDE>
__global__ __launch_bounds__(256) void k_csr(
    const unsigned* __restrict__ part, const int* __restrict__ gcnt,
    int nkeys_total, int* __restrict__ segoff, int* __restrict__ segcnt,
    unsigned* __restrict__ csr) {
    __shared__ __align__(16) unsigned B[CAP];
    __shared__ int hist[NKEY], offs[NKEY + 1], cur[NKEY];
    const int bkt = blockIdx.x;
    const int t = threadIdx.x;
    const unsigned mask = (1u << PACK_SHIFT) - 1u;
    const int tot = min(gcnt[bkt], REGION);
    const int tot4 = tot >> 2;
    const unsigned* src = part + (size_t)bkt * REGION;

    for (int k = t; k < NKEY; k += 256) { hist[k] = 0; cur[k] = 0; }
    __syncthreads();
    // histogram (sentinel-skipped, uint4 reads; gb line-aligned -> src 16B ok)
    for (int i = t; i < tot4; i += 256) {
        const uint4 a = ((const uint4*)src)[i];
        if (a.x != SENTINEL) atomicAdd(&hist[a.x >> PACK_SHIFT], 1);
        if (a.y != SENTINEL) atomicAdd(&hist[a.y >> PACK_SHIFT], 1);
        if (a.z != SENTINEL) atomicAdd(&hist[a.z >> PACK_SHIFT], 1);
        if (a.w != SENTINEL) atomicAdd(&hist[a.w >> PACK_SHIFT], 1);
    }
    for (int i = tot4 * 4 + t; i < tot; i += 256) {
        const unsigned a = src[i];
        if (a != SENTINEL) atomicAdd(&hist[a >> PACK_SHIFT], 1);
    }
    __syncthreads();
    if (t == 0) {
        int acc = 0;
        for (int k = 0; k < NKEY; ++k) { offs[k] = acc; acc += hist[k]; }
        offs[NKEY] = acc;
    }
    __syncthreads();
    // scatter into B (src re-read hits L2)
    for (int i = t; i < tot4; i += 256) {
        const uint4 a = ((const uint4*)src)[i];
        #pragma unroll
        for (int q = 0; q < 4; ++q) {
            const unsigned av = (q == 0) ? a.x : (q == 1) ? a.y : (q == 2) ? a.z : a.w;
            if (av != SENTINEL) {
                const int k = av >> PACK_SHIFT;
                const int pos = offs[k] + atomicAdd(&cur[k], 1);
                if (pos < CAP) B[pos] = av & mask;
            }
        }
    }
    for (int i = tot4 * 4 + t; i < tot; i += 256) {
        const unsigned av = src[i];
        if (av != SENTINEL) {
            const int k = av >> PACK_SHIFT;
            const int pos = offs[k] + atomicAdd(&cur[k], 1);
            if (pos < CAP) B[pos] = av & mask;
        }
    }
    __syncthreads();
    const int total = min(offs[NKEY], CAP);
    unsigned* dst = csr + (size_t)bkt * STRIDE;
    for (int i = t * 4; i + 3 < total; i += 1024)
        *(uint4*)(dst + i) = *(const uint4*)(&B[i]);
    for (int i = (total & ~3) + t; i < total; i += 256) dst[i] = B[i];
    for (int k = t; k < NKEY; k += 256) {
        const int g = bkt * NKEY + k;
        if (g < nkeys_total) {
            const int o0 = min(offs[k], CAP);
            const int o1 = min(offs[k + 1], CAP);
            segoff[g] = bkt * STRIDE + o0;
            segcnt[g] = o1 - o0;
        }
    }
}

// ---------------------------------------------------------------------------
// Kernel F: per-edge gather-reduce, CHANNEL-HALF split across XCD groups.
// blockIdx%8 selects the XCD; XCDs 0-3 process channels 0..63, XCDs 4-7
// channels 64..127 -> per-XCD L2 holds 128 B/row.  [measured R5/R6/R8]
// ---------------------------------------------------------------------------
__global__ __launch_bounds__(256) void k_edge_gather(
    const unsigned* __restrict__ h_u, const unsigned* __restrict__ csrE,
    const int* __restrict__ eoff, const int* __restrict__ ecnt,
    const float* __restrict__ scale, const float* __restrict__ shift,
    unsigned* __restrict__ xe_u) {
    __shared__ int ib[4][EIDX_CAP];
    const int b = blockIdx.x;                   // 0 .. 2*(N_E/4)-1
    const int xcd = b & 7;
    const int half = xcd >> 2;                  // channel half 0/1
    const int grp = (b >> 3) * 4 + (xcd & 3);   // edge group 0..N_E/4-1
    const int wave = threadIdx.x >> 6;
    const int e = grp * 4 + wave;
    const int l = threadIdx.x & 63;
    const int rg = l >> 4, c = l & 15;          // row-in-group, channel-pair
    const int wbase = half * 32 + 2 * c;        // word offset within row
    int o = 0, n = 0;
    if (e < N_E) { o = eoff[e]; n = ecnt[e]; }
    const int nc = min(n, EIDX_CAP);
    int* mi = ib[wave];
    for (int i = l; i < nc; i += 64) mi[i] = (int)csrE[o + i];
    __syncthreads();

    float s[4] = {0.f, 0.f, 0.f, 0.f};
    int j = 0;
    for (; j + 31 < nc; j += 32) {
        const int r0 = mi[j + rg],      r1 = mi[j + 4 + rg];
        const int r2 = mi[j + 8 + rg],  r3 = mi[j + 12 + rg];
        const int r4 = mi[j + 16 + rg], r5 = mi[j + 20 + rg];
        const int r6 = mi[j + 24 + rg], r7 = mi[j + 28 + rg];
        const uint2 u0 = *(const uint2*)(h_u + (size_t)r0 * 64 + wbase);
        const uint2 u1 = *(const uint2*)(h_u + (size_t)r1 * 64 + wbase);
        const uint2 u2 = *(const uint2*)(h_u + (size_t)r2 * 64 + wbase);
        const uint2 u3 = *(const uint2*)(h_u + (size_t)r3 * 64 + wbase);
        const uint2 u4 = *(const uint2*)(h_u + (size_t)r4 * 64 + wbase);
        const uint2 u5 = *(const uint2*)(h_u + (size_t)r5 * 64 + wbase);
        const uint2 u6 = *(const uint2*)(h_u + (size_t)r6 * 64 + wbase);
        const uint2 u7 = *(const uint2*)(h_u + (size_t)r7 * 64 + wbase);
        acc4(s, u0); acc4(s, u1); acc4(s, u2); acc4(s, u3);
        acc4(s, u4); acc4(s, u5); acc4(s, u6); acc4(s, u7);
    }
    for (; j + 15 < nc; j += 16) {
        const int r0 = mi[j + rg],     r1 = mi[j + 4 + rg];
        const int r2 = mi[j + 8 + rg], r3 = mi[j + 12 + rg];
        const uint2 u0 = *(const uint2*)(h_u + (size_t)r0 * 64 + wbase);
        const uint2 u1 = *(const uint2*)(h_u + (size_t)r1 * 64 + wbase);
        const uint2 u2 = *(const uint2*)(h_u + (size_t)r2 * 64 + wbase);
        const uint2 u3 = *(const uint2*)(h_u + (size_t)r3 * 64 + wbase);
        acc4(s, u0); acc4(s, u1); acc4(s, u2); acc4(s, u3);
    }
    for (; j < nc; j += 4) {
        if (j + rg < nc) {
            const int r = mi[j + rg];
            const uint2 u = *(const uint2*)(h_u + (size_t)r * 64 + wbase);
            acc4(s, u);
        }
    }
    // overflow path (n > EIDX_CAP), statistically negligible but correct
    for (int jj = nc; jj < n; jj += 4) {
        if (jj + rg < n) {
            const int r = (int)csrE[o + jj + rg];
            const uint2 u = *(const uint2*)(h_u + (size_t)r * 64 + wbase);
            acc4(s, u);
        }
    }
    #pragma unroll
    for (int k = 0; k < 4; ++k) {
        s[k] += __shfl_xor(s[k], 16);
        s[k] += __shfl_xor(s[k], 32);
    }
    if (e < N_E && rg == 0) {
        float m[4] = {0.f, 0.f, 0.f, 0.f};
        if (n > 0) {
            const float rc = 1.0f / (float)n;
            const float4 sc4 = ((const float4*)scale)[half * 16 + c];
            const float4 sh4 = ((const float4*)shift)[half * 16 + c];
            m[0] = sc4.x * s[0] * rc + sh4.x;
            m[1] = sc4.y * s[1] * rc + sh4.y;
            m[2] = sc4.z * s[2] * rc + sh4.z;
            m[3] = sc4.w * s[3] * rc + sh4.w;
        }
        uint2 pk;
        pk.x = (unsigned)f2bf(m[0]) | ((unsigned)f2bf(m[1]) << 16);
        pk.y = (unsigned)f2bf(m[2]) | ((unsigned)f2bf(m[3]) << 16);
        *(uint2*)(xe_u + (size_t)e * 64 + wbase) = pk;
    }
}

// ---------------------------------------------------------------------------
// Kernel G: per-vertex gather-reduce + ReLU.  Full-row uint4, one wave per
// vertex, LDS index prefetch, 16-row main loop.  [measured R6/R8: ~48 us]
// ---------------------------------------------------------------------------
__global__ __launch_bounds__(256) void k_vert_gather(
    const unsigned* __restrict__ xe_u, const unsigned* __restrict__ csrV,
    const int* __restrict__ voff, const int* __restrict__ vcnt,
    float* __restrict__ out) {
    __shared__ int ib[4][VIDX_CAP];
    const int wave = threadIdx.x >> 6;
    const int v = blockIdx.x * 4 + wave;
    const int l = threadIdx.x & 63;
    const int g = l >> 4, c = l & 15;
    int o = 0, n = 0;
    if (v < N_V) { o = voff[v]; n = vcnt[v]; }
    const int nc = min(n, VIDX_CAP);
    int* mi = ib[wave];
    for (int i = l; i < nc; i += 64) mi[i] = (int)csrV[o + i];
    __syncthreads();

    float s[8] = {0.f, 0.f, 0.f, 0.f, 0.f, 0.f, 0.f, 0.f};
    int j = 0;
    for (; j + 15 < nc; j += 16) {
        const int r0 = mi[j + g],     r1 = mi[j + 4 + g];
        const int r2 = mi[j + 8 + g], r3 = mi[j + 12 + g];
        const uint4 u0 = *(const uint4*)(xe_u + (size_t)r0 * 64 + 4 * c);
        const uint4 u1 = *(const uint4*)(xe_u + (size_t)r1 * 64 + 4 * c);
        const uint4 u2 = *(const uint4*)(xe_u + (size_t)r2 * 64 + 4 * c);
        const uint4 u3 = *(const uint4*)(xe_u + (size_t)r3 * 64 + 4 * c);
        acc8(s, u0); acc8(s, u1); acc8(s, u2); acc8(s, u3);
    }
    for (; j < nc; j += 4) {
        if (j + g < nc) {
            const int r = mi[j + g];
            const uint4 u = *(const uint4*)(xe_u + (size_t)r * 64 + 4 * c);
            acc8(s, u);
        }
    }
    // overflow path (n > VIDX_CAP), statistically negligible but correct
    for (int jj = nc; jj < n; jj += 4) {
        if (jj + g < n) {
            const int r = (int)csrV[o + jj + g];
            const uint4 u = *(const uint4*)(xe_u + (size_t)r * 64 + 4 * c);
            acc8(s, u);
        }
    }
    #pragma unroll
    for (int k = 0; k < 8; ++k) {
        s[k] += __shfl_xor(s[k], 16);
        s[k] += __shfl_xor(s[k], 32);
    }
    if (v < N_V && g == 0) {
        const float rc = 1.0f / (float)max(n, 1);
        float4 r0, r1;
        r0.x = fmaxf(s[0] * rc, 0.f);
        r0.y = fmaxf(s[1] * rc, 0.f);
        r0.z = fmaxf(s[2] * rc, 0.f);
        r0.w = fmaxf(s[3] * rc, 0.f);
        r1.x = fmaxf(s[4] * rc, 0.f);
        r1.y = fmaxf(s[5] * rc, 0.f);
        r1.z = fmaxf(s[6] * rc, 0.f);
        r1.w = fmaxf(s[7] * rc, 0.f);
        ((float4*)out)[(size_t)v * 32 + 2 * c]     = r0;
        ((float4*)out)[(size_t)v * 32 + 2 * c + 1] = r1;
    }
}

// ---------------------------------------------------------------------------
extern "C" void kernel_launch(void* const* d_in, const int* in_sizes, int n_in,
                              void* d_out, int out_size, void* d_ws, size_t ws_size,
                              hipStream_t stream) {
    const float* X     = (const float*)d_in[0];
    const int*   vid   = (const int*)d_in[1];
    const int*   eid   = (const int*)d_in[2];
    const float* W     = (const float*)d_in[3];
    const float* b     = (const float*)d_in[4];
    const float* gamma = (const float*)d_in[5];
    const float* beta  = (const float*)d_in[6];
    float* out = (float*)d_out;

    // workspace layout
    char* ws = (char*)d_ws;
    unsigned* h_u   = (unsigned*)ws;  ws += (size_t)N_V * 64 * 4;            // 25.6 MB
    unsigned* xe_u  = (unsigned*)ws;  ws += (size_t)N_E * 64 * 4;            //  5.1 MB
    unsigned* partE = (unsigned*)ws;  ws += (size_t)NB_E * EB_REGION * 4;    // 11.5 MB
    unsigned* partV = (unsigned*)ws;  ws += (size_t)NB_V * VB_REGION * 4;    // 12.8 MB
    unsigned* csrE  = (unsigned*)ws;  ws += (size_t)NB_E * EB_SORT * 4;      //  7.4 MB
    unsigned* csrV  = (unsigned*)ws;  ws += (size_t)NB_V * VB_SORT * 4;      //  7.2 MB
    int* eoff = (int*)ws;             ws += (size_t)N_E * 4;
    int* ecnt = (int*)ws;             ws += (size_t)N_E * 4;
    int* voff = (int*)ws;             ws += (size_t)N_V * 4;
    int* vcnt = (int*)ws;             ws += (size_t)N_V * 4;
    // --- zeroed region ---
    char* zbase = ws;
    int*   gcntE = (int*)ws;          ws += (size_t)NB_E * 4;
    int*   gcntV = (int*)ws;          ws += (size_t)NB_V * 4;
    float* sums  = (float*)ws;        ws += 256 * 4;
    // --- end zeroed region ---
    float* scale = (float*)ws;        ws += 128 * 4;
    float* shift = (float*)ws;        ws += 128 * 4;

    hipMemsetAsync(zbase, 0, (size_t)((char*)scale - zbase), stream);

    k_gemm_mfma<<<GEMM_BLOCKS, 256, 0, stream>>>(X, W, b, h_u);
    k_bn_stats<<<BN_BLOCKS, 256, 0, stream>>>(h_u, sums);
    k_bn_final<<<1, 128, 0, stream>>>(sums, gamma, beta, scale, shift);

    k_sort_dual<<<SORT_BLOCKS, 256, 0, stream>>>(vid, eid, gcntE, gcntV,
                                                 partE, partV);

    k_csr<64, 17, EB_SORT, EB_REGION, EB_SORT>
        <<<NB_E, 256, 0, stream>>>(partE, gcntE, N_E, eoff, ecnt, csrE);
    k_csr<256, 15, VB_SORT, VB_REGION, VB_SORT>
        <<<NB_V, 256, 0, stream>>>(partV, gcntV, N_V, voff, vcnt, csrV);

    // edge: 2 channel-halves x (N_E/4) groups; blockIdx%8 pins XCD,
    // XCDs 0-3 -> half 0, XCDs 4-7 -> half 1.
    k_edge_gather<<<(N_E / 4) * 2, 256, 0, stream>>>(h_u, csrE, eoff, ecnt,
                                                     scale, shift, xe_u);
    // vertex: full-row, one wave per vertex
    k_vert_gather<<<(N_V + 3) / 4, 256, 0, stream>>>(xe_u, csrV, voff, vcnt,
                                                     out);
}

// Round 11
// 259.181 us; speedup vs baseline: 3.0023x; 1.1009x over previous
//
#include <hip/hip_runtime.h>
#include <hip/hip_bf16.h>

#define N_V 100000
#define N_E 20000
#define N_P 1600000
#define FDIM 128
#define HDIM 128
#define BN_EPS 1e-5f

// ---- bucket/sort geometry ----
#define SORT_C 4096
#define SORT_BLOCKS ((N_P + SORT_C - 1) / SORT_C)   // 391
#define NB_E 313                   // edge buckets (64 edges each)
#define EB_SHIFT 6
#define EB_REGION 9216             // slots per edge bucket region
#define EB_SORT 5888               // max valid entries per bucket (mean 5112)
#define NB_V 391                   // vertex buckets (256 vertices each)
#define VB_SHIFT 8
#define VB_REGION 8192
#define VB_SORT 4608               // max valid entries per bucket (mean 4096)
#define SENTINEL 0xFFFFFFFFu

#define EIDX_CAP 192   // per-wave LDS index buffer, edges (mean deg 80)
#define VIDX_CAP 64    // per-wave LDS index buffer, vertices (mean deg 16)

#define GEMM_BLOCKS 625
#define WT_STRIDE 136   // 128 + 8 bf16 pad -> 2-way-only LDS conflicts
#define BN_BLOCKS 400
#define BN_RPB 250

typedef __attribute__((ext_vector_type(8))) short short8;
typedef __attribute__((ext_vector_type(4))) float floatx4;

__device__ __forceinline__ float bf_lo(unsigned u) {
    return __uint_as_float(u << 16);
}
__device__ __forceinline__ float bf_hi(unsigned u) {
    return __uint_as_float(u & 0xffff0000u);
}
// fp32 -> bf16 bits, round-to-nearest-even
__device__ __forceinline__ unsigned short f2bf(float f) {
    unsigned u = __float_as_uint(f);
    return (unsigned short)((u + 0x7fffu + ((u >> 16) & 1u)) >> 16);
}

// accumulate 4 bf16 channels from one uint2 into s[0..3]
__device__ __forceinline__ void acc4(float* s, const uint2& u) {
    s[0] += bf_lo(u.x); s[1] += bf_hi(u.x);
    s[2] += bf_lo(u.y); s[3] += bf_hi(u.y);
}

// accumulate 8 bf16 channels from one uint4 into s[0..7]
__device__ __forceinline__ void acc8(float* s, const uint4& u) {
    s[0] += bf_lo(u.x); s[1] += bf_hi(u.x);
    s[2] += bf_lo(u.y); s[3] += bf_hi(u.y);
    s[4] += bf_lo(u.z); s[5] += bf_hi(u.z);
    s[6] += bf_lo(u.w); s[7] += bf_hi(u.w);
}

// ===========================================================================
// Fused-launch shared-memory unions.  [R10->R11: the 6 middle kernels each
// run at ~1.2-2.4 blocks/CU (latency-bound, GPU underutilized) and serialize
// on one stream; streams+events are forbidden under graph capture, so
// concurrency is expressed by block-level fusion of independent kernels.]
// ===========================================================================
union SmemGemmSort {
    struct {
        unsigned short WTs[FDIM * WT_STRIDE];                  // ~34 KB
    } g;
    struct {
        unsigned stageE[SORT_C];                               // 16 KB
        unsigned stageV[SORT_C];                               // 16 KB
        int histE[NB_E], curE[NB_E], offsE[NB_E], gbaseE[NB_E];
        int histV[NB_V], curV[NB_V], offsV[NB_V], gbaseV[NB_V];
        int partial[256];
    } s;                                                       // ~45 KB
};

union SmemBnCsr {
    struct {
        unsigned B[EB_SORT];        // max(EB_SORT, VB_SORT)
        int hist[256];              // max(64, 256)
        int offs[257];
        int cur[256];
    } c;                            // ~26 KB
    struct {
        float ls[128], lss[128];
    } b;
};

// ---------------------------------------------------------------------------
// gemm body: h = X @ W + b via bf16 MFMA, computed as C^T = W^T · X^T.
// ---------------------------------------------------------------------------
__device__ void gemm_body(int bid, unsigned short* WTs,
                          const float* __restrict__ X,
                          const float* __restrict__ W,
                          const float* __restrict__ bias,
                          unsigned* __restrict__ h_u) {
    const int t = threadIdx.x;
    for (int idx = t; idx < FDIM * HDIM; idx += 256) {
        const int k = idx >> 7, m = idx & 127;
        WTs[m * WT_STRIDE + k] = f2bf(W[idx]);
    }
    __syncthreads();

    const int wave = t >> 6, lane = t & 63;
    const int quad = lane >> 4, sub = lane & 15;
    const int nstrips = N_V / 16;  // 6250, exact

    for (int s = bid * 4 + wave; s < nstrips; s += GEMM_BLOCKS * 4) {
        const int row0 = s * 16;
        short8 xf[4];
        const float* xp = X + (size_t)(row0 + sub) * FDIM + quad * 8;
        #pragma unroll
        for (int kt = 0; kt < 4; ++kt) {
            const float4 a = *(const float4*)(xp + kt * 32);
            const float4 b2 = *(const float4*)(xp + kt * 32 + 4);
            short8 f;
            f[0] = (short)f2bf(a.x);  f[1] = (short)f2bf(a.y);
            f[2] = (short)f2bf(a.z);  f[3] = (short)f2bf(a.w);
            f[4] = (short)f2bf(b2.x); f[5] = (short)f2bf(b2.y);
            f[6] = (short)f2bf(b2.z); f[7] = (short)f2bf(b2.w);
            xf[kt] = f;
        }
        #pragma unroll
        for (int tile = 0; tile < 8; ++tile) {
            floatx4 acc = {0.f, 0.f, 0.f, 0.f};
            const unsigned short* wp =
                WTs + (tile * 16 + sub) * WT_STRIDE + quad * 8;
            #pragma unroll
            for (int kt = 0; kt < 4; ++kt) {
                const short8 af = *(const short8*)(wp + kt * 32);
                acc = __builtin_amdgcn_mfma_f32_16x16x32_bf16(af, xf[kt], acc,
                                                              0, 0, 0);
            }
            const int ch = tile * 16 + quad * 4;
            const float4 bb = *(const float4*)(bias + ch);
            const float c0 = acc[0] + bb.x, c1 = acc[1] + bb.y;
            const float c2 = acc[2] + bb.z, c3 = acc[3] + bb.w;
            const unsigned lo = (unsigned)f2bf(c0) | ((unsigned)f2bf(c1) << 16);
            const unsigned hi = (unsigned)f2bf(c2) | ((unsigned)f2bf(c3) << 16);
            uint2* dst = (uint2*)(h_u + (size_t)(row0 + sub) * 64 + (ch >> 1));
            *dst = make_uint2(lo, hi);
        }
    }
}

// ---------------------------------------------------------------------------
// sort body: dual-direction LDS-staged chunk sort, line-aligned full-line
// flush.  [R9 lesson: direct global scatter = 16x write amplification;
// bucket+full-line-flush is the right structure.  int4 loads, uint4 writes.]
// ---------------------------------------------------------------------------
__device__ void sort_body(int bid, SmemGemmSort* sm,
                          const int* __restrict__ vid,
                          const int* __restrict__ eid,
                          int* __restrict__ gcntE, int* __restrict__ gcntV,
                          unsigned* __restrict__ partE,
                          unsigned* __restrict__ partV) {
    unsigned* stageE = sm->s.stageE;
    unsigned* stageV = sm->s.stageV;
    int* histE = sm->s.histE; int* curE = sm->s.curE;
    int* offsE = sm->s.offsE; int* gbaseE = sm->s.gbaseE;
    int* histV = sm->s.histV; int* curV = sm->s.curV;
    int* offsV = sm->s.offsV; int* gbaseV = sm->s.gbaseV;
    int* partial = sm->s.partial;
    const int t = threadIdx.x;
    const int p0 = bid * SORT_C;
    const int n = min(SORT_C, N_P - p0);         // always divisible by 4
    const int n4 = n >> 2;
    const int4* e4p = (const int4*)(eid + p0);
    const int4* v4p = (const int4*)(vid + p0);

    for (int k = t; k < NB_E; k += 256) histE[k] = 0;
    for (int k = t; k < NB_V; k += 256) histV[k] = 0;
    __syncthreads();
    for (int i = t; i < n4; i += 256) {
        const int4 e4 = e4p[i];
        const int4 v4 = v4p[i];
        atomicAdd(&histE[((unsigned)e4.x) >> EB_SHIFT], 1);
        atomicAdd(&histE[((unsigned)e4.y) >> EB_SHIFT], 1);
        atomicAdd(&histE[((unsigned)e4.z) >> EB_SHIFT], 1);
        atomicAdd(&histE[((unsigned)e4.w) >> EB_SHIFT], 1);
        atomicAdd(&histV[((unsigned)v4.x) >> VB_SHIFT], 1);
        atomicAdd(&histV[((unsigned)v4.y) >> VB_SHIFT], 1);
        atomicAdd(&histV[((unsigned)v4.z) >> VB_SHIFT], 1);
        atomicAdd(&histV[((unsigned)v4.w) >> VB_SHIFT], 1);
    }
    __syncthreads();
    // scan E
    {
        constexpr int G = (NB_E + 255) / 256;
        int loc[G]; int s = 0;
        #pragma unroll
        for (int g = 0; g < G; ++g) {
            int idx = t * G + g; loc[g] = s;
            if (idx < NB_E) s += histE[idx];
        }
        partial[t] = s;
        __syncthreads();
        for (int d = 1; d < 256; d <<= 1) {
            int x = (t >= d) ? partial[t - d] : 0;
            __syncthreads(); partial[t] += x; __syncthreads();
        }
        const int base = t ? partial[t - 1] : 0;
        #pragma unroll
        for (int g = 0; g < G; ++g) {
            int idx = t * G + g;
            if (idx < NB_E) { offsE[idx] = base + loc[g]; curE[idx] = base + loc[g]; }
        }
        __syncthreads();
    }
    // scan V
    {
        constexpr int G = (NB_V + 255) / 256;
        int loc[G]; int s = 0;
        #pragma unroll
        for (int g = 0; g < G; ++g) {
            int idx = t * G + g; loc[g] = s;
            if (idx < NB_V) s += histV[idx];
        }
        partial[t] = s;
        __syncthreads();
        for (int d = 1; d < 256; d <<= 1) {
            int x = (t >= d) ? partial[t - d] : 0;
            __syncthreads(); partial[t] += x; __syncthreads();
        }
        const int base = t ? partial[t - 1] : 0;
        #pragma unroll
        for (int g = 0; g < G; ++g) {
            int idx = t * G + g;
            if (idx < NB_V) { offsV[idx] = base + loc[g]; curV[idx] = base + loc[g]; }
        }
        __syncthreads();
    }
    // place both directions (4 entries per thread, int4 loads)
    for (int i = t; i < n4; i += 256) {
        const int4 e4 = e4p[i];
        const int4 v4 = v4p[i];
        #pragma unroll
        for (int q = 0; q < 4; ++q) {
            const int ev = (q == 0) ? e4.x : (q == 1) ? e4.y : (q == 2) ? e4.z : e4.w;
            const int vv = (q == 0) ? v4.x : (q == 1) ? v4.y : (q == 2) ? v4.z : v4.w;
            const unsigned pkE = ((unsigned)(ev & 63) << 17) | (unsigned)vv;
            stageE[atomicAdd(&curE[(unsigned)ev >> EB_SHIFT], 1)] = pkE;
            const unsigned pkV = ((unsigned)(vv & 255) << 15) | (unsigned)ev;
            stageV[atomicAdd(&curV[(unsigned)vv >> VB_SHIFT], 1)] = pkV;
        }
    }
    __syncthreads();
    // allocate line-aligned global space
    for (int k = t; k < NB_E; k += 256) {
        const int c = histE[k];
        gbaseE[k] = c ? atomicAdd(&gcntE[k], (c + 15) & ~15) : 0;
    }
    for (int k = t; k < NB_V; k += 256) {
        const int c = histV[k];
        gbaseV[k] = c ? atomicAdd(&gcntV[k], (c + 15) & ~15) : 0;
    }
    __syncthreads();
    // flush E (uint4 writes; cpad multiple of 16, dst 64B aligned)
    for (int k = t >> 3; k < NB_E; k += 32) {
        const int c = histE[k];
        if (c == 0) continue;
        int cpad = (c + 15) & ~15;
        const int gb = gbaseE[k];
        if (gb >= EB_REGION) continue;
        cpad = min(cpad, EB_REGION - gb);
        unsigned* dst = partE + (size_t)k * EB_REGION + gb;
        const int lo = offsE[k];
        for (int j = (t & 7) * 4; j + 3 < cpad; j += 32) {
            uint4 w;
            w.x = (j + 0 < c) ? stageE[lo + j + 0] : SENTINEL;
            w.y = (j + 1 < c) ? stageE[lo + j + 1] : SENTINEL;
            w.z = (j + 2 < c) ? stageE[lo + j + 2] : SENTINEL;
            w.w = (j + 3 < c) ? stageE[lo + j + 3] : SENTINEL;
            *(uint4*)(dst + j) = w;
        }
    }
    // flush V
    for (int k = t >> 3; k < NB_V; k += 32) {
        const int c = histV[k];
        if (c == 0) continue;
        int cpad = (c + 15) & ~15;
        const int gb = gbaseV[k];
        if (gb >= VB_REGION) continue;
        cpad = min(cpad, VB_REGION - gb);
        unsigned* dst = partV + (size_t)k * VB_REGION + gb;
        const int lo = offsV[k];
        for (int j = (t & 7) * 4; j + 3 < cpad; j += 32) {
            uint4 w;
            w.x = (j + 0 < c) ? stageV[lo + j + 0] : SENTINEL;
            w.y = (j + 1 < c) ? stageV[lo + j + 1] : SENTINEL;
            w.z = (j + 2 < c) ? stageV[lo + j + 2] : SENTINEL;
            w.w = (j + 3 < c) ? stageV[lo + j + 3] : SENTINEL;
            *(uint4*)(dst + j) = w;
        }
    }
}

// ---------------------------------------------------------------------------
// K1: gemm (blocks 0..624) || sort_dual (blocks 625..1015).  Independent
// input->workspace chains; fusing them overlaps two latency-bound kernels.
// ---------------------------------------------------------------------------
__global__ __launch_bounds__(256) void k_gemm_sort(
    const float* __restrict__ X, const float* __restrict__ W,
    const float* __restrict__ bias, unsigned* __restrict__ h_u,
    const int* __restrict__ vid, const int* __restrict__ eid,
    int* __restrict__ gcntE, int* __restrict__ gcntV,
    unsigned* __restrict__ partE, unsigned* __restrict__ partV) {
    __shared__ __align__(16) SmemGemmSort sm;
    const int b = blockIdx.x;
    if (b < GEMM_BLOCKS)
        gemm_body(b, sm.g.WTs, X, W, bias, h_u);
    else
        sort_body(b - GEMM_BLOCKS, &sm, vid, eid, gcntE, gcntV, partE, partV);
}

// ---------------------------------------------------------------------------
// bn_stats body: per-channel sum & sumsq of bf16 h.  uint4/lane.
// ---------------------------------------------------------------------------
__device__ void bn_body(int bid, float* ls, float* lss,
                        const unsigned* __restrict__ h_u,
                        float* __restrict__ sums) {
    const int t = threadIdx.x;
    const int c8 = t & 15;            // channel octet: ch 8*c8 .. 8*c8+7
    const int rw = t >> 4;            // 16 row lanes
    const int r0 = bid * BN_RPB;
    const int r1 = min(r0 + BN_RPB, N_V);
    float s[8] = {0.f,0.f,0.f,0.f,0.f,0.f,0.f,0.f};
    float ss[8] = {0.f,0.f,0.f,0.f,0.f,0.f,0.f,0.f};
    for (int r = r0 + rw; r < r1; r += 16) {
        const uint4 u = *(const uint4*)(h_u + (size_t)r * 64 + c8 * 4);
        const float x0 = bf_lo(u.x), x1 = bf_hi(u.x);
        const float x2 = bf_lo(u.y), x3 = bf_hi(u.y);
        const float x4 = bf_lo(u.z), x5 = bf_hi(u.z);
        const float x6 = bf_lo(u.w), x7 = bf_hi(u.w);
        s[0]+=x0; ss[0]+=x0*x0;  s[1]+=x1; ss[1]+=x1*x1;
        s[2]+=x2; ss[2]+=x2*x2;  s[3]+=x3; ss[3]+=x3*x3;
        s[4]+=x4; ss[4]+=x4*x4;  s[5]+=x5; ss[5]+=x5*x5;
        s[6]+=x6; ss[6]+=x6*x6;  s[7]+=x7; ss[7]+=x7*x7;
    }
    #pragma unroll
    for (int k = 0; k < 8; ++k) {
        s[k]  += __shfl_xor(s[k], 16);  s[k]  += __shfl_xor(s[k], 32);
        ss[k] += __shfl_xor(ss[k], 16); ss[k] += __shfl_xor(ss[k], 32);
    }
    for (int k = t; k < 128; k += 256) { ls[k] = 0.f; lss[k] = 0.f; }
    __syncthreads();
    if ((t & 63) < 16) {
        #pragma unroll
        for (int k = 0; k < 8; ++k) {
            atomicAdd(&ls[c8 * 8 + k], s[k]);
            atomicAdd(&lss[c8 * 8 + k], ss[k]);
        }
    }
    __syncthreads();
    if (t < 128) {
        atomicAdd(&sums[t],       ls[t]);
        atomicAdd(&sums[128 + t], lss[t]);
    }
}

// ---------------------------------------------------------------------------
// csr body: bucket region -> compact sorted CSR.  Sentinels skipped inline
// (no ballot-compact), uint4 reads, uint4 B write-out.  [R7 lesson: keep
// the sort -> register-reduce structure; LDS-atomic accumulation is 27x
// slower.]
// ---------------------------------------------------------------------------
template <int NKEY, int PACK_SHIFT, int CAP, int REGION, int STRIDE>
__device__ void csr_body(int bkt, const unsigned* __restrict__ part,
                         const int* __restrict__ gcnt, int nkeys_total,
                         int* __restrict__ segoff, int* __restrict__ segcnt,
                         unsigned* __restrict__ csr,
                         unsigned* B, int* hist, int* offs, int* cur) {
    const int t = threadIdx.x;
    const unsigned mask = (1u << PACK_SHIFT) - 1u;
    const int tot = min(gcnt[bkt], REGION);
    const int tot4 = tot >> 2;
    const unsigned* src = part + (size_t)bkt * REGION;

    for (int k = t; k < NKEY; k += 256) { hist[k] = 0; cur[k] = 0; }
    __syncthreads();
    for (int i = t; i < tot4; i += 256) {
        const uint4 a = ((const uint4*)src)[i];
        if (a.x != SENTINEL) atomicAdd(&hist[a.x >> PACK_SHIFT], 1);
        if (a.y != SENTINEL) atomicAdd(&hist[a.y >> PACK_SHIFT], 1);
        if (a.z != SENTINEL) atomicAdd(&hist[a.z >> PACK_SHIFT], 1);
        if (a.w != SENTINEL) atomicAdd(&hist[a.w >> PACK_SHIFT], 1);
    }
    for (int i = tot4 * 4 + t; i < tot; i += 256) {
        const unsigned a = src[i];
        if (a != SENTINEL) atomicAdd(&hist[a >> PACK_SHIFT], 1);
    }
    __syncthreads();
    if (t == 0) {
        int acc = 0;
        for (int k = 0; k < NKEY; ++k) { offs[k] = acc; acc += hist[k]; }
        offs[NKEY] = acc;
    }
    __syncthreads();
    for (int i = t; i < tot4; i += 256) {
        const uint4 a = ((const uint4*)src)[i];
        #pragma unroll
        for (int q = 0; q < 4; ++q) {
            const unsigned av = (q == 0) ? a.x : (q == 1) ? a.y : (q == 2) ? a.z : a.w;
            if (av != SENTINEL) {
                const int k = av >> PACK_SHIFT;
                const int pos = offs[k] + atomicAdd(&cur[k], 1);
                if (pos < CAP) B[pos] = av & mask;
            }
        }
    }
    for (int i = tot4 * 4 + t; i < tot; i += 256) {
        const unsigned av = src[i];
        if (av != SENTINEL) {
            const int k = av >> PACK_SHIFT;
            const int pos = offs[k] + atomicAdd(&cur[k], 1);
            if (pos < CAP) B[pos] = av & mask;
        }
    }
    __syncthreads();
    const int total = min(offs[NKEY], CAP);
    unsigned* dst = csr + (size_t)bkt * STRIDE;
    for (int i = t * 4; i + 3 < total; i += 1024)
        *(uint4*)(dst + i) = *(const uint4*)(&B[i]);
    for (int i = (total & ~3) + t; i < total; i += 256) dst[i] = B[i];
    for (int k = t; k < NKEY; k += 256) {
        const int g = bkt * NKEY + k;
        if (g < nkeys_total) {
            const int o0 = min(offs[k], CAP);
            const int o1 = min(offs[k + 1], CAP);
            segoff[g] = bkt * STRIDE + o0;
            segcnt[g] = o1 - o0;
        }
    }
}

// ---------------------------------------------------------------------------
// K2: bn_stats (0..399) || csrE (400..712) || csrV (713..1103).  All three
// depend only on K1's outputs and are mutually independent.
// ---------------------------------------------------------------------------
__global__ __launch_bounds__(256) void k_bn_csr(
    const unsigned* __restrict__ h_u, float* __restrict__ sums,
    const unsigned* __restrict__ partE, const int* __restrict__ gcntE,
    int* __restrict__ eoff, int* __restrict__ ecnt, unsigned* __restrict__ csrE,
    const unsigned* __restrict__ partV, const int* __restrict__ gcntV,
    int* __restrict__ voff, int* __restrict__ vcnt, unsigned* __restrict__ csrV) {
    __shared__ __align__(16) SmemBnCsr sm;
    const int b = blockIdx.x;
    if (b < BN_BLOCKS) {
        bn_body(b, sm.b.ls, sm.b.lss, h_u, sums);
    } else if (b < BN_BLOCKS + NB_E) {
        csr_body<64, 17, EB_SORT, EB_REGION, EB_SORT>(
            b - BN_BLOCKS, partE, gcntE, N_E, eoff, ecnt, csrE,
            sm.c.B, sm.c.hist, sm.c.offs, sm.c.cur);
    } else {
        csr_body<256, 15, VB_SORT, VB_REGION, VB_SORT>(
            b - BN_BLOCKS - NB_E, partV, gcntV, N_V, voff, vcnt, csrV,
            sm.c.B, sm.c.hist, sm.c.offs, sm.c.cur);
    }
}

// ---------------------------------------------------------------------------
// Kernel C: finalize BN -> scale/shift
// ---------------------------------------------------------------------------
__global__ void k_bn_final(const float* __restrict__ sums,
                           const float* __restrict__ gamma,
                           const float* __restrict__ beta,
                           float* __restrict__ scale, float* __restrict__ shift) {
    const int c = threadIdx.x;
    const float inv_n = 1.0f / (float)N_V;
    const float mu  = sums[c] * inv_n;
    const float var = sums[128 + c] * inv_n - mu * mu;
    const float inv = rsqrtf(var + BN_EPS);
    const float sc  = gamma[c] * inv;
    scale[c] = sc;
    shift[c] = beta[c] - mu * sc;
}

// ---------------------------------------------------------------------------
// Kernel F: per-edge gather-reduce, CHANNEL-HALF split across XCD groups.
// blockIdx%8 selects the XCD; XCDs 0-3 process channels 0..63, XCDs 4-7
// channels 64..127 -> per-XCD L2 holds 128 B/row.  [measured R5/R6/R8]
// ---------------------------------------------------------------------------
__global__ __launch_bounds__(256) void k_edge_gather(
    const unsigned* __restrict__ h_u, const unsigned* __restrict__ csrE,
    const int* __restrict__ eoff, const int* __restrict__ ecnt,
    const float* __restrict__ scale, const float* __restrict__ shift,
    unsigned* __restrict__ xe_u) {
    __shared__ int ib[4][EIDX_CAP];
    const int b = blockIdx.x;                   // 0 .. 2*(N_E/4)-1
    const int xcd = b & 7;
    const int half = xcd >> 2;                  // channel half 0/1
    const int grp = (b >> 3) * 4 + (xcd & 3);   // edge group 0..N_E/4-1
    const int wave = threadIdx.x >> 6;
    const int e = grp * 4 + wave;
    const int l = threadIdx.x & 63;
    const int rg = l >> 4, c = l & 15;          // row-in-group, channel-pair
    const int wbase = half * 32 + 2 * c;        // word offset within row
    int o = 0, n = 0;
    if (e < N_E) { o = eoff[e]; n = ecnt[e]; }
    const int nc = min(n, EIDX_CAP);
    int* mi = ib[wave];
    for (int i = l; i < nc; i += 64) mi[i] = (int)csrE[o + i];
    __syncthreads();

    float s[4] = {0.f, 0.f, 0.f, 0.f};
    int j = 0;
    for (; j + 31 < nc; j += 32) {
        const int r0 = mi[j + rg],      r1 = mi[j + 4 + rg];
        const int r2 = mi[j + 8 + rg],  r3 = mi[j + 12 + rg];
        const int r4 = mi[j + 16 + rg], r5 = mi[j + 20 + rg];
        const int r6 = mi[j + 24 + rg], r7 = mi[j + 28 + rg];
        const uint2 u0 = *(const uint2*)(h_u + (size_t)r0 * 64 + wbase);
        const uint2 u1 = *(const uint2*)(h_u + (size_t)r1 * 64 + wbase);
        const uint2 u2 = *(const uint2*)(h_u + (size_t)r2 * 64 + wbase);
        const uint2 u3 = *(const uint2*)(h_u + (size_t)r3 * 64 + wbase);
        const uint2 u4 = *(const uint2*)(h_u + (size_t)r4 * 64 + wbase);
        const uint2 u5 = *(const uint2*)(h_u + (size_t)r5 * 64 + wbase);
        const uint2 u6 = *(const uint2*)(h_u + (size_t)r6 * 64 + wbase);
        const uint2 u7 = *(const uint2*)(h_u + (size_t)r7 * 64 + wbase);
        acc4(s, u0); acc4(s, u1); acc4(s, u2); acc4(s, u3);
        acc4(s, u4); acc4(s, u5); acc4(s, u6); acc4(s, u7);
    }
    for (; j + 15 < nc; j += 16) {
        const int r0 = mi[j + rg],     r1 = mi[j + 4 + rg];
        const int r2 = mi[j + 8 + rg], r3 = mi[j + 12 + rg];
        const uint2 u0 = *(const uint2*)(h_u + (size_t)r0 * 64 + wbase);
        const uint2 u1 = *(const uint2*)(h_u + (size_t)r1 * 64 + wbase);
        const uint2 u2 = *(const uint2*)(h_u + (size_t)r2 * 64 + wbase);
        const uint2 u3 = *(const uint2*)(h_u + (size_t)r3 * 64 + wbase);
        acc4(s, u0); acc4(s, u1); acc4(s, u2); acc4(s, u3);
    }
    for (; j < nc; j += 4) {
        if (j + rg < nc) {
            const int r = mi[j + rg];
            const uint2 u = *(const uint2*)(h_u + (size_t)r * 64 + wbase);
            acc4(s, u);
        }
    }
    // overflow path (n > EIDX_CAP), statistically negligible but correct
    for (int jj = nc; jj < n; jj += 4) {
        if (jj + rg < n) {
            const int r = (int)csrE[o + jj + rg];
            const uint2 u = *(const uint2*)(h_u + (size_t)r * 64 + wbase);
            acc4(s, u);
        }
    }
    #pragma unroll
    for (int k = 0; k < 4; ++k) {
        s[k] += __shfl_xor(s[k], 16);
        s[k] += __shfl_xor(s[k], 32);
    }
    if (e < N_E && rg == 0) {
        float m[4] = {0.f, 0.f, 0.f, 0.f};
        if (n > 0) {
            const float rc = 1.0f / (float)n;
            const float4 sc4 = ((const float4*)scale)[half * 16 + c];
            const float4 sh4 = ((const float4*)shift)[half * 16 + c];
            m[0] = sc4.x * s[0] * rc + sh4.x;
            m[1] = sc4.y * s[1] * rc + sh4.y;
            m[2] = sc4.z * s[2] * rc + sh4.z;
            m[3] = sc4.w * s[3] * rc + sh4.w;
        }
        uint2 pk;
        pk.x = (unsigned)f2bf(m[0]) | ((unsigned)f2bf(m[1]) << 16);
        pk.y = (unsigned)f2bf(m[2]) | ((unsigned)f2bf(m[3]) << 16);
        *(uint2*)(xe_u + (size_t)e * 64 + wbase) = pk;
    }
}

// ---------------------------------------------------------------------------
// Kernel G: per-vertex gather-reduce + ReLU.  Full-row uint4, one wave per
// vertex, LDS index prefetch, 16-row main loop.  [measured R6/R8/R10: ~48 us]
// ---------------------------------------------------------------------------
__global__ __launch_bounds__(256) void k_vert_gather(
    const unsigned* __restrict__ xe_u, const unsigned* __restrict__ csrV,
    const int* __restrict__ voff, const int* __restrict__ vcnt,
    float* __restrict__ out) {
    __shared__ int ib[4][VIDX_CAP];
    const int wave = threadIdx.x >> 6;
    const int v = blockIdx.x * 4 + wave;
    const int l = threadIdx.x & 63;
    const int g = l >> 4, c = l & 15;
    int o = 0, n = 0;
    if (v < N_V) { o = voff[v]; n = vcnt[v]; }
    const int nc = min(n, VIDX_CAP);
    int* mi = ib[wave];
    for (int i = l; i < nc; i += 64) mi[i] = (int)csrV[o + i];
    __syncthreads();

    float s[8] = {0.f, 0.f, 0.f, 0.f, 0.f, 0.f, 0.f, 0.f};
    int j = 0;
    for (; j + 15 < nc; j += 16) {
        const int r0 = mi[j + g],     r1 = mi[j + 4 + g];
        const int r2 = mi[j + 8 + g], r3 = mi[j + 12 + g];
        const uint4 u0 = *(const uint4*)(xe_u + (size_t)r0 * 64 + 4 * c);
        const uint4 u1 = *(const uint4*)(xe_u + (size_t)r1 * 64 + 4 * c);
        const uint4 u2 = *(const uint4*)(xe_u + (size_t)r2 * 64 + 4 * c);
        const uint4 u3 = *(const uint4*)(xe_u + (size_t)r3 * 64 + 4 * c);
        acc8(s, u0); acc8(s, u1); acc8(s, u2); acc8(s, u3);
    }
    for (; j < nc; j += 4) {
        if (j + g < nc) {
            const int r = mi[j + g];
            const uint4 u = *(const uint4*)(xe_u + (size_t)r * 64 + 4 * c);
            acc8(s, u);
        }
    }
    // overflow path (n > VIDX_CAP), statistically negligible but correct
    for (int jj = nc; jj < n; jj += 4) {
        if (jj + g < n) {
            const int r = (int)csrV[o + jj + g];
            const uint4 u = *(const uint4*)(xe_u + (size_t)r * 64 + 4 * c);
            acc8(s, u);
        }
    }
    #pragma unroll
    for (int k = 0; k < 8; ++k) {
        s[k] += __shfl_xor(s[k], 16);
        s[k] += __shfl_xor(s[k], 32);
    }
    if (v < N_V && g == 0) {
        const float rc = 1.0f / (float)max(n, 1);
        float4 r0, r1;
        r0.x = fmaxf(s[0] * rc, 0.f);
        r0.y = fmaxf(s[1] * rc, 0.f);
        r0.z = fmaxf(s[2] * rc, 0.f);
        r0.w = fmaxf(s[3] * rc, 0.f);
        r1.x = fmaxf(s[4] * rc, 0.f);
        r1.y = fmaxf(s[5] * rc, 0.f);
        r1.z = fmaxf(s[6] * rc, 0.f);
        r1.w = fmaxf(s[7] * rc, 0.f);
        ((float4*)out)[(size_t)v * 32 + 2 * c]     = r0;
        ((float4*)out)[(size_t)v * 32 + 2 * c + 1] = r1;
    }
}

// ---------------------------------------------------------------------------
extern "C" void kernel_launch(void* const* d_in, const int* in_sizes, int n_in,
                              void* d_out, int out_size, void* d_ws, size_t ws_size,
                              hipStream_t stream) {
    const float* X     = (const float*)d_in[0];
    const int*   vid   = (const int*)d_in[1];
    const int*   eid   = (const int*)d_in[2];
    const float* W     = (const float*)d_in[3];
    const float* b     = (const float*)d_in[4];
    const float* gamma = (const float*)d_in[5];
    const float* beta  = (const float*)d_in[6];
    float* out = (float*)d_out;

    // workspace layout
    char* ws = (char*)d_ws;
    unsigned* h_u   = (unsigned*)ws;  ws += (size_t)N_V * 64 * 4;            // 25.6 MB
    unsigned* xe_u  = (unsigned*)ws;  ws += (size_t)N_E * 64 * 4;            //  5.1 MB
    unsigned* partE = (unsigned*)ws;  ws += (size_t)NB_E * EB_REGION * 4;    // 11.5 MB
    unsigned* partV = (unsigned*)ws;  ws += (size_t)NB_V * VB_REGION * 4;    // 12.8 MB
    unsigned* csrE  = (unsigned*)ws;  ws += (size_t)NB_E * EB_SORT * 4;      //  7.4 MB
    unsigned* csrV  = (unsigned*)ws;  ws += (size_t)NB_V * VB_SORT * 4;      //  7.2 MB
    int* eoff = (int*)ws;             ws += (size_t)N_E * 4;
    int* ecnt = (int*)ws;             ws += (size_t)N_E * 4;
    int* voff = (int*)ws;             ws += (size_t)N_V * 4;
    int* vcnt = (int*)ws;             ws += (size_t)N_V * 4;
    // --- zeroed region ---
    char* zbase = ws;
    int*   gcntE = (int*)ws;          ws += (size_t)NB_E * 4;
    int*   gcntV = (int*)ws;          ws += (size_t)NB_V * 4;
    float* sums  = (float*)ws;        ws += 256 * 4;
    // --- end zeroed region ---
    float* scale = (float*)ws;        ws += 128 * 4;
    float* shift = (float*)ws;        ws += 128 * 4;

    hipMemsetAsync(zbase, 0, (size_t)((char*)scale - zbase), stream);

    // K1: gemm || sort_dual (independent chains, fused for concurrency)
    k_gemm_sort<<<GEMM_BLOCKS + SORT_BLOCKS, 256, 0, stream>>>(
        X, W, b, h_u, vid, eid, gcntE, gcntV, partE, partV);

    // K2: bn_stats || csrE || csrV (all depend only on K1)
    k_bn_csr<<<BN_BLOCKS + NB_E + NB_V, 256, 0, stream>>>(
        h_u, sums, partE, gcntE, eoff, ecnt, csrE,
        partV, gcntV, voff, vcnt, csrV);

    k_bn_final<<<1, 128, 0, stream>>>(sums, gamma, beta, scale, shift);

    // edge: 2 channel-halves x (N_E/4) groups; blockIdx%8 pins XCD,
    // XCDs 0-3 -> half 0, XCDs 4-7 -> half 1.
    k_edge_gather<<<(N_E / 4) * 2, 256, 0, stream>>>(h_u, csrE, eoff, ecnt,
                                                     scale, shift, xe_u);
    // vertex: full-row, one wave per vertex
    k_vert_gather<<<(N_V + 3) / 4, 256, 0, stream>>>(xe_u, csrV, voff, vcnt,
                                                     out);
}